// Round 4
// baseline (1262.134 us; speedup 1.0000x reference)
//
#include <hip/hip_runtime.h>
#include <hip/hip_fp16.h>

#define N_NODES 100000
#define N_EDGES 1600000
#define N_GRAPHS 128
#define EMBED 32
#define HID 64
#define NBUCK 1563          // ceil(N_NODES/64)
#define CAP 1280            // per-bucket edge capacity (avg 1023, sigma ~32)

__device__ __forceinline__ float rdlane(float v, int l) {
    return __int_as_float(__builtin_amdgcn_readlane(__float_as_int(v), l));
}

// ---------- embed gather -> fp16 ----------
__global__ void k_embed(const int* __restrict__ ids,
                        const float* __restrict__ table,
                        __half2* __restrict__ x0h) {
    int gid = blockIdx.x * blockDim.x + threadIdx.x;   // N*16 threads exactly
    int n = gid >> 4, q = gid & 15;
    int id = ids[n];
    float2 t = ((const float2*)(table + (size_t)id * EMBED))[q];
    x0h[(size_t)n * 16 + q] = __floats2half2_rn(t.x, t.y);
}

// ---------- bucket edges by dst>>6 (packed: src | local_dst<<17) ----------
__global__ void k_bucket(const int* __restrict__ src, const int* __restrict__ dst,
                         int* __restrict__ bcnt, int* __restrict__ ebuf) {
    int e = blockIdx.x * 256 + threadIdx.x;            // E exactly divisible
    int d = dst[e];
    int s = src[e];
    int b = d >> 6;
    int pos = atomicAdd(&bcnt[b], 1);
    if (pos < CAP) ebuf[b * CAP + pos] = s | ((d & 63) << 17);
}

// ---------- fused conv1: LDS-atomic aggregate + reg-weight update ----------
// block = 1 bucket (64 nodes); 256 thr = 8 half-waves (gather) / 4 waves (update)
__global__ __launch_bounds__(256, 4)
void k_conv1f(const int* __restrict__ bcnt, const int* __restrict__ ebuf,
              const __half* __restrict__ x0s,          // [N][32] half
              const float* __restrict__ Wl, const float* __restrict__ Wr,
              const float* __restrict__ bias,
              __half* __restrict__ h1h) {              // [N][64] half
    __shared__ float acc[64][EMBED];                   // 8 KB
    __shared__ int cnt_s[64];
    int tid = threadIdx.x;
    int bkt = blockIdx.x;
    int n0 = bkt << 6;
    int nn = min(64, N_NODES - n0);
    for (int i = tid; i < 64 * EMBED; i += 256) ((float*)acc)[i] = 0.f;
    if (tid < 64) cnt_s[tid] = 0;
    __syncthreads();

    int cntE = min(bcnt[bkt], CAP);
    const int* eb = ebuf + bkt * CAP;
    int hw = tid >> 5, ch = tid & 31;
    for (int i0 = hw * 8; i0 < cntE; i0 += 64) {       // 8 half-waves x 8 edges
        int m = cntE - i0; if (m > 8) m = 8;
        int4 p0 = ((const int4*)(eb + i0))[0];         // always in-bounds (<=CAP)
        int4 p1 = ((const int4*)(eb + i0))[1];
        int pe[8] = {p0.x, p0.y, p0.z, p0.w, p1.x, p1.y, p1.z, p1.w};
        float v[8]; int ld[8];
        #pragma unroll
        for (int q = 0; q < 8; ++q) if (q < m) {
            ld[q] = pe[q] >> 17;
            v[q] = __half2float(x0s[(size_t)(pe[q] & 0x1FFFF) * EMBED + ch]);
        }
        #pragma unroll
        for (int q = 0; q < 8; ++q) if (q < m) {
            atomicAdd(&acc[ld[q]][ch], v[q]);
            if (ch == 0) atomicAdd(&cnt_s[ld[q]], 1);
        }
    }
    __syncthreads();

    // update: lane = output channel; weights in registers
    int wv = tid >> 6, lane = tid & 63;
    float wl[EMBED], wr[EMBED];
    #pragma unroll
    for (int k = 0; k < EMBED; ++k) {
        wl[k] = Wl[lane * EMBED + k];
        wr[k] = Wr[lane * EMBED + k];
    }
    float bo = bias[lane];
    for (int ni = 0; ni < 16; ++ni) {
        int n = wv * 16 + ni;
        if (n >= nn) break;
        float accv = acc[n][lane & 31];                            // lane k holds sum_k
        float ownv = __half2float(x0s[(size_t)(n0 + n) * EMBED + (lane & 31)]);
        float inv = 1.f / fmaxf((float)cnt_s[n], 1.f);
        float sa = 0.f, sb = 0.f, ra = 0.f, rb = 0.f;
        #pragma unroll
        for (int k = 0; k < EMBED; k += 2) {
            sa = fmaf(rdlane(accv, k),     wl[k],     sa);
            sb = fmaf(rdlane(accv, k + 1), wl[k + 1], sb);
            ra = fmaf(rdlane(ownv, k),     wr[k],     ra);
            rb = fmaf(rdlane(ownv, k + 1), wr[k + 1], rb);
        }
        float r = fmaf(sa + sb, inv, ra + rb) + bo;
        h1h[(size_t)(n0 + n) * HID + lane] = __float2half(fmaxf(r, 0.f));
    }
}

// ---------- fused conv2 ----------
__global__ __launch_bounds__(256, 2)
void k_conv2f(const int* __restrict__ bcnt, const int* __restrict__ ebuf,
              const __half* __restrict__ h1s,          // [N][64] half
              const float* __restrict__ Wl, const float* __restrict__ Wr,
              const float* __restrict__ bias,
              __half* __restrict__ h2h) {              // [N][64] half
    __shared__ float acc[64][HID];                     // 16 KB
    __shared__ int cnt_s[64];
    int tid = threadIdx.x;
    int bkt = blockIdx.x;
    int n0 = bkt << 6;
    int nn = min(64, N_NODES - n0);
    for (int i = tid; i < 64 * HID; i += 256) ((float*)acc)[i] = 0.f;
    if (tid < 64) cnt_s[tid] = 0;
    __syncthreads();

    int cntE = min(bcnt[bkt], CAP);
    const int* eb = ebuf + bkt * CAP;
    int wv = tid >> 6, lane = tid & 63;
    for (int i0 = wv * 8; i0 < cntE; i0 += 32) {       // 4 waves x 8 edges
        int m = cntE - i0; if (m > 8) m = 8;
        int4 p0 = ((const int4*)(eb + i0))[0];
        int4 p1 = ((const int4*)(eb + i0))[1];
        int pe[8] = {p0.x, p0.y, p0.z, p0.w, p1.x, p1.y, p1.z, p1.w};
        float v[8]; int ld[8];
        #pragma unroll
        for (int q = 0; q < 8; ++q) if (q < m) {
            ld[q] = pe[q] >> 17;
            v[q] = __half2float(h1s[(size_t)(pe[q] & 0x1FFFF) * HID + lane]);
        }
        #pragma unroll
        for (int q = 0; q < 8; ++q) if (q < m) {
            atomicAdd(&acc[ld[q]][lane], v[q]);
            if (lane == 0) atomicAdd(&cnt_s[ld[q]], 1);
        }
    }
    __syncthreads();

    // update: lane = output channel; 128 weight VGPRs
    float wl[HID], wr[HID];
    #pragma unroll
    for (int k = 0; k < HID; ++k) {
        wl[k] = Wl[lane * HID + k];
        wr[k] = Wr[lane * HID + k];
    }
    float bo = bias[lane];
    for (int ni = 0; ni < 16; ++ni) {
        int n = wv * 16 + ni;
        if (n >= nn) break;
        float accv = acc[n][lane];
        float ownv = __half2float(h1s[(size_t)(n0 + n) * HID + lane]);
        float inv = 1.f / fmaxf((float)cnt_s[n], 1.f);
        float sa = 0.f, sb = 0.f, ra = 0.f, rb = 0.f;
        #pragma unroll
        for (int k = 0; k < HID; k += 2) {
            sa = fmaf(rdlane(accv, k),     wl[k],     sa);
            sb = fmaf(rdlane(accv, k + 1), wl[k + 1], sb);
            ra = fmaf(rdlane(ownv, k),     wr[k],     ra);
            rb = fmaf(rdlane(ownv, k + 1), wr[k + 1], rb);
        }
        float r = fmaf(sa + sb, inv, ra + rb) + bo;
        h2h[(size_t)(n0 + n) * HID + lane] = __float2half(fmaxf(r, 0.f));
    }
}

// ---------- pool + final head ----------
__device__ inline int lower_bound_batch(const int* b, int val) {
    int lo = 0, hi = N_NODES;
    while (lo < hi) {
        int mid = (lo + hi) >> 1;
        if (b[mid] < val) lo = mid + 1; else hi = mid;
    }
    return lo;
}

__global__ __launch_bounds__(256)
void k_pool_final(const __half* __restrict__ h2h, const int* __restrict__ batch,
                  const float* __restrict__ W_lin, const float* __restrict__ b_lin,
                  float* __restrict__ out) {
    __shared__ float red[4][64];
    __shared__ float pool[64];
    int g = blockIdx.x;
    int start = lower_bound_batch(batch, g);
    int end   = lower_bound_batch(batch, g + 1);
    int w = threadIdx.x >> 6, lane = threadIdx.x & 63;
    float acc = 0.0f;
    for (int n = start + w; n < end; n += 4)
        acc += __half2float(h2h[(size_t)n * HID + lane]);
    red[w][lane] = acc;
    __syncthreads();
    if (w == 0) {
        float tot = red[0][lane] + red[1][lane] + red[2][lane] + red[3][lane];
        pool[lane] = tot / fmaxf((float)(end - start), 1.0f);
    }
    __syncthreads();
    if (threadIdx.x < 2) {
        int c = threadIdx.x;
        float s = b_lin[c];
        #pragma unroll 8
        for (int k = 0; k < HID; ++k)
            s += pool[k] * W_lin[c * HID + k];
        out[g * 2 + c] = s;
    }
}

extern "C" void kernel_launch(void* const* d_in, const int* in_sizes, int n_in,
                              void* d_out, int out_size, void* d_ws, size_t ws_size,
                              hipStream_t stream) {
    const int*   node_ids = (const int*)d_in[0];
    const int*   ei       = (const int*)d_in[1];
    const int*   batch    = (const int*)d_in[2];
    const float* table    = (const float*)d_in[3];
    const float* W1l      = (const float*)d_in[4];
    const float* W1r      = (const float*)d_in[5];
    const float* b1       = (const float*)d_in[6];
    const float* W2l      = (const float*)d_in[7];
    const float* W2r      = (const float*)d_in[8];
    const float* b2       = (const float*)d_in[9];
    const float* Wlin     = (const float*)d_in[10];
    const float* blin     = (const float*)d_in[11];
    const int* src = ei;
    const int* dst = ei + N_EDGES;

    int* bcnt = (int*)d_ws;                            // NBUCK (zeroed), padded to 1568
    int* ebuf = bcnt + 1568;                           // NBUCK*CAP ints = 8.0 MB
    __half* x0s = (__half*)(ebuf + (size_t)NBUCK * CAP);   // 32N half = 6.4 MB
    __half* h1s = x0s + (size_t)32 * N_NODES;          // 64N half = 12.8 MB
    __half* h2s = h1s + (size_t)64 * N_NODES;          // 64N half = 12.8 MB

    hipMemsetAsync(bcnt, 0, 1568 * sizeof(int), stream);

    k_embed <<<N_NODES * 16 / 256, 256, 0, stream>>>(node_ids, table, (__half2*)x0s);
    k_bucket<<<N_EDGES / 256,      256, 0, stream>>>(src, dst, bcnt, ebuf);
    k_conv1f<<<NBUCK, 256, 0, stream>>>(bcnt, ebuf, x0s, W1l, W1r, b1, h1s);
    k_conv2f<<<NBUCK, 256, 0, stream>>>(bcnt, ebuf, h1s, W2l, W2r, b2, h2s);
    k_pool_final<<<N_GRAPHS, 256, 0, stream>>>(h2s, batch, Wlin, blin, (float*)d_out);
}

// Round 5
// 376.458 us; speedup vs baseline: 3.3527x; 3.3527x over previous
//
#include <hip/hip_runtime.h>
#include <hip/hip_fp16.h>

#define N_NODES 100000
#define N_EDGES 1600000
#define N_GRAPHS 128
#define EMBED 32
#define HID 64
#define NBUCK 1563             // ceil(N_NODES/64)
#define CAP 1280               // per-bucket capacity (mean 1024, sigma 32 -> +8s)
#define CHUNK 128              // edges per agg group
#define NGRP (N_EDGES / CHUNK) // 12500

// ---------- embed gather -> fp16 ----------
__global__ void k_embed(const int* __restrict__ ids,
                        const float* __restrict__ table,
                        __half2* __restrict__ x0h) {
    int gid = blockIdx.x * blockDim.x + threadIdx.x;   // N*16 threads exactly
    int n = gid >> 4, q = gid & 15;
    int id = ids[n];
    float2 t = ((const float2*)(table + (size_t)id * EMBED))[q];
    x0h[(size_t)n * 16 + q] = __floats2half2_rn(t.x, t.y);
}

// ---------- level-1 bucket by dst>>6 (packed: src | local_dst<<17) ----------
__global__ void k_bucket(const int* __restrict__ src, const int* __restrict__ dst,
                         int* __restrict__ bcnt, int* __restrict__ ebuf) {
    int e = blockIdx.x * 256 + threadIdx.x;            // E divisible by 256
    int d = dst[e];
    int s = src[e];
    int b = d >> 6;
    int pos = atomicAdd(&bcnt[b * 16], 1);             // 1 counter per cache line
    if (pos < CAP) ebuf[b * CAP + pos] = s | ((d & 63) << 17);
}

// ---------- scan bucket counts -> dense CSR bucket bases ----------
__global__ __launch_bounds__(1024)
void k_bscan(const int* __restrict__ bcnt, int* __restrict__ bbase,
             int* __restrict__ off_total) {
    __shared__ int leaf[1024];
    int t = threadIdx.x;
    int i0 = 2 * t, i1 = 2 * t + 1;
    int a = (i0 < NBUCK) ? min(bcnt[i0 * 16], CAP) : 0;
    int b = (i1 < NBUCK) ? min(bcnt[i1 * 16], CAP) : 0;
    leaf[t] = a + b;
    __syncthreads();
    for (int d = 1; d < 1024; d <<= 1) {
        int v = (t >= d) ? leaf[t - d] : 0;
        __syncthreads();
        leaf[t] += v;
        __syncthreads();
    }
    int excl = leaf[t] - (a + b);
    if (i0 < NBUCK) bbase[i0] = excl;
    if (i1 < NBUCK) bbase[i1] = excl + a;
    if (t == 1023) off_total[0] = leaf[1023];          // = off[N_NODES]
}

// ---------- level-2: in-LDS counting sort per bucket -> ssrc, deg, off ----------
__global__ __launch_bounds__(256)
void k_sortb(const int* __restrict__ bcnt, const int* __restrict__ ebuf,
             const int* __restrict__ bbase,
             int* __restrict__ ssrc, int* __restrict__ deg, int* __restrict__ off) {
    __shared__ int hist[64], loff[64], cur[64];
    __shared__ int sbuf[CAP];
    __shared__ int obuf[CAP];
    int tid = threadIdx.x, bkt = blockIdx.x;
    int cntE = min(bcnt[bkt * 16], CAP);
    if (tid < 64) hist[tid] = 0;
    __syncthreads();
    const int* eb = ebuf + bkt * CAP;
    for (int i = tid; i < cntE; i += 256) {
        int p = eb[i];
        sbuf[i] = p;
        atomicAdd(&hist[p >> 17], 1);                  // native int LDS atomic
    }
    __syncthreads();
    if (tid < 64) {
        int v = hist[tid];
        int inc = v;
        for (int d = 1; d < 64; d <<= 1) {
            int u = __shfl_up(inc, d);
            if (tid >= d) inc += u;
        }
        loff[tid] = inc - v;                           // exclusive
        cur[tid] = 0;
    }
    __syncthreads();
    for (int i = tid; i < cntE; i += 256) {
        int p = sbuf[i];
        int l = p >> 17;
        int pos = loff[l] + atomicAdd(&cur[l], 1);
        obuf[pos] = p & 0x1FFFF;
    }
    __syncthreads();
    int base = bbase[bkt];
    for (int i = tid; i < cntE; i += 256) ssrc[base + i] = obuf[i];
    int n0 = bkt << 6;
    int nn = min(64, N_NODES - n0);
    if (tid < nn) {
        deg[n0 + tid] = hist[tid];
        off[n0 + tid] = base + loff[tid];
    }
}

// ---------- edge-streaming segmented aggregation (unchanged from R3) ----------
template<int L>
__global__ __launch_bounds__(256)
void k_agg(const int* __restrict__ ssrc, const int* __restrict__ off,
           const __half2* __restrict__ feat,   // [N][L] half2
           float2* __restrict__ agg)           // [N][L] float2
{
    int tid = blockIdx.x * 256 + threadIdx.x;
    int grp = tid / L;
    int lane = tid % L;
    if (grp >= NGRP) return;
    int base = grp * CHUNK;
    int end  = base + CHUNK;
    int lo = 0, hi = N_NODES - 1;                      // largest d: off[d] <= base
    while (lo < hi) {
        int mid = (lo + hi + 1) >> 1;
        if (off[mid] <= base) lo = mid; else hi = mid - 1;
    }
    int d = lo;
    bool dstart_in = (off[d] >= base);
    int next = off[d + 1];
    float2 acc = make_float2(0.f, 0.f);
    for (int j = base; j < end; j += 4) {
        int s0 = ssrc[j], s1 = ssrc[j + 1], s2 = ssrc[j + 2], s3 = ssrc[j + 3];
        __half2 v0 = feat[s0 * L + lane];
        __half2 v1 = feat[s1 * L + lane];
        __half2 v2 = feat[s2 * L + lane];
        __half2 v3 = feat[s3 * L + lane];
        #pragma unroll
        for (int q = 0; q < 4; ++q) {
            int jj = j + q;
            if (jj >= next) {
                if (dstart_in) {
                    agg[d * L + lane] = acc;
                } else {
                    unsafeAtomicAdd(&((float*)agg)[(d * L + lane) * 2],     acc.x);
                    unsafeAtomicAdd(&((float*)agg)[(d * L + lane) * 2 + 1], acc.y);
                }
                acc = make_float2(0.f, 0.f);
                dstart_in = true;
                d++;
                while (off[d + 1] <= jj) d++;
                next = off[d + 1];
            }
            __half2 v = (q == 0) ? v0 : (q == 1) ? v1 : (q == 2) ? v2 : v3;
            float2 f = __half22float2(v);
            acc.x += f.x; acc.y += f.y;
        }
    }
    if (dstart_in && next == end) {
        agg[d * L + lane] = acc;
    } else {
        unsafeAtomicAdd(&((float*)agg)[(d * L + lane) * 2],     acc.x);
        unsafeAtomicAdd(&((float*)agg)[(d * L + lane) * 2 + 1], acc.y);
    }
}

// ---------- dense update 1 (unchanged from R3) ----------
__global__ __launch_bounds__(512)
void k_update1(const float* __restrict__ agg1, const int* __restrict__ deg,
               const __half2* __restrict__ x0h,
               const float* __restrict__ W_l, const float* __restrict__ W_r,
               const float* __restrict__ b, __half* __restrict__ h1h) {
    __shared__ float sWl[HID * 34];
    __shared__ float sWr[HID * 34];
    __shared__ float srow[8][4][64];
    for (int i = threadIdx.x; i < HID * EMBED; i += 512) {
        int o = i >> 5, k = i & 31;
        sWl[o * 34 + k] = W_l[i];
        sWr[o * 34 + k] = W_r[i];
    }
    int w = threadIdx.x >> 6, lane = threadIdx.x & 63;
    int nb = blockIdx.x * 32 + w * 4;
    #pragma unroll
    for (int i = 0; i < 4; ++i) {
        int n = nb + i;
        if (lane < 32) {
            float inv = 1.0f / fmaxf((float)deg[n], 1.0f);
            srow[w][i][lane] = agg1[n * 32 + lane] * inv;
        } else {
            int ch = lane - 32;
            float2 f = __half22float2(x0h[n * 16 + (ch >> 1)]);
            srow[w][i][lane] = ((ch & 1) == 0) ? f.x : f.y;
        }
    }
    __syncthreads();
    float bo = b[lane];
    float a0 = 0, a1 = 0, a2 = 0, a3 = 0;
    #pragma unroll
    for (int k = 0; k < 32; ++k) {
        float wl = sWl[lane * 34 + k];
        float wr = sWr[lane * 34 + k];
        a0 += srow[w][0][k] * wl + srow[w][0][32 + k] * wr;
        a1 += srow[w][1][k] * wl + srow[w][1][32 + k] * wr;
        a2 += srow[w][2][k] * wl + srow[w][2][32 + k] * wr;
        a3 += srow[w][3][k] * wl + srow[w][3][32 + k] * wr;
    }
    h1h[(nb + 0) * HID + lane] = __float2half(fmaxf(a0 + bo, 0.f));
    h1h[(nb + 1) * HID + lane] = __float2half(fmaxf(a1 + bo, 0.f));
    h1h[(nb + 2) * HID + lane] = __float2half(fmaxf(a2 + bo, 0.f));
    h1h[(nb + 3) * HID + lane] = __float2half(fmaxf(a3 + bo, 0.f));
}

// ---------- dense update 2 (unchanged from R3) ----------
__global__ __launch_bounds__(512)
void k_update2(const float* __restrict__ agg2, const int* __restrict__ deg,
               const __half* __restrict__ h1h,
               const float* __restrict__ W_l, const float* __restrict__ W_r,
               const float* __restrict__ b, __half* __restrict__ h2h) {
    __shared__ float sWl[HID * 66];
    __shared__ float sWr[HID * 66];
    __shared__ float srow[8][4][128];
    for (int i = threadIdx.x; i < HID * HID; i += 512) {
        int o = i >> 6, k = i & 63;
        sWl[o * 66 + k] = W_l[i];
        sWr[o * 66 + k] = W_r[i];
    }
    int w = threadIdx.x >> 6, lane = threadIdx.x & 63;
    int nb = blockIdx.x * 32 + w * 4;
    #pragma unroll
    for (int i = 0; i < 4; ++i) {
        int n = nb + i;
        float inv = 1.0f / fmaxf((float)deg[n], 1.0f);
        srow[w][i][lane]      = agg2[n * 64 + lane] * inv;
        srow[w][i][64 + lane] = __half2float(h1h[n * 64 + lane]);
    }
    __syncthreads();
    float bo = b[lane];
    float a0 = 0, a1 = 0, a2 = 0, a3 = 0;
    #pragma unroll
    for (int k = 0; k < 64; ++k) {
        float wl = sWl[lane * 66 + k];
        float wr = sWr[lane * 66 + k];
        a0 += srow[w][0][k] * wl + srow[w][0][64 + k] * wr;
        a1 += srow[w][1][k] * wl + srow[w][1][64 + k] * wr;
        a2 += srow[w][2][k] * wl + srow[w][2][64 + k] * wr;
        a3 += srow[w][3][k] * wl + srow[w][3][64 + k] * wr;
    }
    h2h[(nb + 0) * HID + lane] = __float2half(fmaxf(a0 + bo, 0.f));
    h2h[(nb + 1) * HID + lane] = __float2half(fmaxf(a1 + bo, 0.f));
    h2h[(nb + 2) * HID + lane] = __float2half(fmaxf(a2 + bo, 0.f));
    h2h[(nb + 3) * HID + lane] = __float2half(fmaxf(a3 + bo, 0.f));
}

// ---------- pool + final head ----------
__device__ inline int lower_bound_batch(const int* b, int val) {
    int lo = 0, hi = N_NODES;
    while (lo < hi) {
        int mid = (lo + hi) >> 1;
        if (b[mid] < val) lo = mid + 1; else hi = mid;
    }
    return lo;
}

__global__ __launch_bounds__(256)
void k_pool_final(const __half* __restrict__ h2h, const int* __restrict__ batch,
                  const float* __restrict__ W_lin, const float* __restrict__ b_lin,
                  float* __restrict__ out) {
    __shared__ float red[4][64];
    __shared__ float pool[64];
    int g = blockIdx.x;
    int start = lower_bound_batch(batch, g);
    int end   = lower_bound_batch(batch, g + 1);
    int w = threadIdx.x >> 6, lane = threadIdx.x & 63;
    float acc = 0.0f;
    for (int n = start + w; n < end; n += 4)
        acc += __half2float(h2h[(size_t)n * HID + lane]);
    red[w][lane] = acc;
    __syncthreads();
    if (w == 0) {
        float tot = red[0][lane] + red[1][lane] + red[2][lane] + red[3][lane];
        pool[lane] = tot / fmaxf((float)(end - start), 1.0f);
    }
    __syncthreads();
    if (threadIdx.x < 2) {
        int c = threadIdx.x;
        float s = b_lin[c];
        #pragma unroll 8
        for (int k = 0; k < HID; ++k)
            s += pool[k] * W_lin[c * HID + k];
        out[g * 2 + c] = s;
    }
}

extern "C" void kernel_launch(void* const* d_in, const int* in_sizes, int n_in,
                              void* d_out, int out_size, void* d_ws, size_t ws_size,
                              hipStream_t stream) {
    const int*   node_ids = (const int*)d_in[0];
    const int*   ei       = (const int*)d_in[1];
    const int*   batch    = (const int*)d_in[2];
    const float* table    = (const float*)d_in[3];
    const float* W1l      = (const float*)d_in[4];
    const float* W1r      = (const float*)d_in[5];
    const float* b1       = (const float*)d_in[6];
    const float* W2l      = (const float*)d_in[7];
    const float* W2r      = (const float*)d_in[8];
    const float* b2       = (const float*)d_in[9];
    const float* Wlin     = (const float*)d_in[10];
    const float* blin     = (const float*)d_in[11];
    const int* src = ei;
    const int* dst = ei + N_EDGES;

    // ints: bcnt[1568*16] bbase[1568] deg[N] off[N+1] ebuf[NBUCK*CAP] ssrc[E] pad3
    int* bcnt  = (int*)d_ws;                                 // 25088 (line-padded)
    int* bbase = bcnt + 1568 * 16;                           // 1568
    int* ideg  = bbase + 1568;                               // N
    int* ioff  = ideg + N_NODES;                             // N+1
    int* ebuf  = ioff + N_NODES + 1;                         // NBUCK*CAP
    int* issrc = ebuf + (size_t)NBUCK * CAP;                 // E
    size_t int_total = 1568 * 16 + 1568 + N_NODES + (N_NODES + 1)
                     + (size_t)NBUCK * CAP + N_EDGES;        // 3827297
    float*   aggAB = (float*)d_ws + int_total + 3;           // 16B aligned, 64N floats
    __half2* x0h   = (__half2*)(aggAB + 64 * N_NODES);       // 16N half2
    __half*  h1h   = (__half*)(x0h + 16 * N_NODES);          // 64N half
    __half*  h2h   = h1h + 64 * N_NODES;                     // 64N half

    hipMemsetAsync(bcnt, 0, 1568 * 16 * sizeof(int), stream);
    hipMemsetAsync(aggAB, 0, 32 * N_NODES * sizeof(float), stream);

    k_embed <<<N_NODES * 16 / 256, 256, 0, stream>>>(node_ids, table, x0h);
    k_bucket<<<N_EDGES / 256,      256, 0, stream>>>(src, dst, bcnt, ebuf);
    k_bscan <<<1, 1024, 0, stream>>>(bcnt, bbase, ioff + N_NODES);
    k_sortb <<<NBUCK, 256, 0, stream>>>(bcnt, ebuf, bbase, issrc, ideg, ioff);

    k_agg<16><<<(NGRP * 16 + 255) / 256, 256, 0, stream>>>(issrc, ioff, x0h,
                                                           (float2*)aggAB);
    k_update1<<<N_NODES / 32, 512, 0, stream>>>(aggAB, ideg, x0h, W1l, W1r, b1, h1h);

    hipMemsetAsync(aggAB, 0, 64 * N_NODES * sizeof(float), stream);
    k_agg<32><<<(NGRP * 32 + 255) / 256, 256, 0, stream>>>(issrc, ioff,
                                                           (const __half2*)h1h,
                                                           (float2*)aggAB);
    k_update2<<<N_NODES / 32, 512, 0, stream>>>(aggAB, ideg, h1h, W2l, W2r, b2, h2h);

    k_pool_final<<<N_GRAPHS, 256, 0, stream>>>(h2h, batch, Wlin, blin, (float*)d_out);
}

// Round 6
// 333.917 us; speedup vs baseline: 3.7798x; 1.1274x over previous
//
#include <hip/hip_runtime.h>
#include <hip/hip_fp16.h>

#define N_NODES 100000
#define N_EDGES 1600000
#define N_GRAPHS 128
#define EMBED 32
#define HID 64
#define NBUCK 1563             // ceil(N_NODES/64)
#define CAP 1280               // per-bucket capacity (mean 1024, sigma 32)
#define CHUNK 128              // edges per agg group
#define NGRP (N_EDGES / CHUNK) // 12500
#define PTILE 16384            // edges per partition block
#define NPART ((N_EDGES + PTILE - 1) / PTILE)  // 98

// ---------- embed gather -> fp16 ----------
__global__ void k_embed(const int* __restrict__ ids,
                        const float* __restrict__ table,
                        __half2* __restrict__ x0h) {
    int gid = blockIdx.x * blockDim.x + threadIdx.x;   // N*16 threads exactly
    int n = gid >> 4, q = gid & 15;
    int id = ids[n];
    float2 t = ((const float2*)(table + (size_t)id * EMBED))[q];
    x0h[(size_t)n * 16 + q] = __floats2half2_rn(t.x, t.y);
}

// ---------- LDS-staged partition by dst>>6 (line-granular global writes) ----------
__global__ __launch_bounds__(256)
void k_part(const int* __restrict__ src, const int* __restrict__ dst,
            int* __restrict__ bcnt, int* __restrict__ ebuf) {
    __shared__ int hist[NBUCK];    // per-bucket counts (preserved)
    __shared__ int loff[NBUCK];    // local exclusive offsets (preserved)
    __shared__ int cur[NBUCK];     // scatter cursors
    __shared__ int gbase[NBUCK];   // global base per bucket
    __shared__ int sbuf[PTILE];    // staged packed edges, bucket-major
    __shared__ int wsum[4];
    int tid = threadIdx.x;
    int e0 = blockIdx.x * PTILE;
    int cnt = min(PTILE, N_EDGES - e0);
    for (int i = tid; i < NBUCK; i += 256) hist[i] = 0;
    __syncthreads();
    for (int i = tid; i < cnt; i += 256)
        atomicAdd(&hist[dst[e0 + i] >> 6], 1);         // native int LDS atomic
    __syncthreads();
    // exclusive scan over 1563 buckets: thread t owns buckets [7t, 7t+7)
    int b0 = tid * 7;
    int l[7]; int s = 0;
    #pragma unroll
    for (int k = 0; k < 7; ++k) {
        int idx = b0 + k;
        int v = (idx < NBUCK) ? hist[idx] : 0;
        l[k] = s; s += v;
    }
    int lane = tid & 63, wv = tid >> 6;
    int inc = s;
    for (int d = 1; d < 64; d <<= 1) {
        int u = __shfl_up(inc, d);
        if (lane >= d) inc += u;
    }
    if (lane == 63) wsum[wv] = inc;
    __syncthreads();
    int wbase = 0;
    for (int w = 0; w < wv; ++w) wbase += wsum[w];
    int tpre = wbase + inc - s;
    #pragma unroll
    for (int k = 0; k < 7; ++k) {
        int idx = b0 + k;
        if (idx < NBUCK) { loff[idx] = tpre + l[k]; cur[idx] = tpre + l[k]; }
    }
    __syncthreads();
    // reserve global space (one int atomic per non-empty bucket)
    for (int b = tid; b < NBUCK; b += 256) {
        int c = hist[b];
        gbase[b] = (c > 0) ? atomicAdd(&bcnt[b * 16], c) : 0;
    }
    // scatter into LDS staging
    for (int i = tid; i < cnt; i += 256) {
        int d = dst[e0 + i];
        int sv = src[e0 + i];
        int b = d >> 6;
        int pos = atomicAdd(&cur[b], 1);
        sbuf[pos] = sv | ((d & 63) << 17);
    }
    __syncthreads();
    // coalesced copy-out: 16 quarter-wave groups, bucket-strided
    int grp = tid >> 4, qlane = tid & 15;
    for (int b = grp; b < NBUCK; b += 16) {
        int c = hist[b];
        if (c == 0) continue;
        int lo = loff[b];
        int gb = gbase[b];
        for (int j = qlane; j < c; j += 16) {
            int gpos = gb + j;
            if (gpos < CAP) ebuf[b * CAP + gpos] = sbuf[lo + j];
        }
    }
}

// ---------- scan bucket counts -> dense CSR bucket bases ----------
__global__ __launch_bounds__(1024)
void k_bscan(const int* __restrict__ bcnt, int* __restrict__ bbase,
             int* __restrict__ off_total) {
    __shared__ int leaf[1024];
    int t = threadIdx.x;
    int i0 = 2 * t, i1 = 2 * t + 1;
    int a = (i0 < NBUCK) ? min(bcnt[i0 * 16], CAP) : 0;
    int b = (i1 < NBUCK) ? min(bcnt[i1 * 16], CAP) : 0;
    leaf[t] = a + b;
    __syncthreads();
    for (int d = 1; d < 1024; d <<= 1) {
        int v = (t >= d) ? leaf[t - d] : 0;
        __syncthreads();
        leaf[t] += v;
        __syncthreads();
    }
    int excl = leaf[t] - (a + b);
    if (i0 < NBUCK) bbase[i0] = excl;
    if (i1 < NBUCK) bbase[i1] = excl + a;
    if (t == 1023) off_total[0] = leaf[1023];
}

// ---------- level-2: in-LDS counting sort per bucket -> ssrc, deg, off ----------
__global__ __launch_bounds__(256)
void k_sortb(const int* __restrict__ bcnt, const int* __restrict__ ebuf,
             const int* __restrict__ bbase,
             int* __restrict__ ssrc, int* __restrict__ deg, int* __restrict__ off) {
    __shared__ int hist[64], loff[64], cur[64];
    __shared__ int sbuf[CAP];
    __shared__ int obuf[CAP];
    int tid = threadIdx.x, bkt = blockIdx.x;
    int cntE = min(bcnt[bkt * 16], CAP);
    if (tid < 64) hist[tid] = 0;
    __syncthreads();
    const int* eb = ebuf + bkt * CAP;
    for (int i = tid; i < cntE; i += 256) {
        int p = eb[i];
        sbuf[i] = p;
        atomicAdd(&hist[p >> 17], 1);
    }
    __syncthreads();
    if (tid < 64) {
        int v = hist[tid];
        int inc = v;
        for (int d = 1; d < 64; d <<= 1) {
            int u = __shfl_up(inc, d);
            if (tid >= d) inc += u;
        }
        loff[tid] = inc - v;
        cur[tid] = 0;
    }
    __syncthreads();
    for (int i = tid; i < cntE; i += 256) {
        int p = sbuf[i];
        int l = p >> 17;
        int pos = loff[l] + atomicAdd(&cur[l], 1);
        obuf[pos] = p & 0x1FFFF;
    }
    __syncthreads();
    int base = bbase[bkt];
    for (int i = tid; i < cntE; i += 256) ssrc[base + i] = obuf[i];
    int n0 = bkt << 6;
    int nn = min(64, N_NODES - n0);
    if (tid < nn) {
        deg[n0 + tid] = hist[tid];
        off[n0 + tid] = base + loff[tid];
    }
}

// ---------- edge-streaming segmented aggregation ----------
template<int L>
__global__ __launch_bounds__(256)
void k_agg(const int* __restrict__ ssrc, const int* __restrict__ off,
           const __half2* __restrict__ feat,   // [N][L] half2
           float2* __restrict__ agg)           // [N][L] float2
{
    int tid = blockIdx.x * 256 + threadIdx.x;
    int grp = tid / L;
    int lane = tid % L;
    if (grp >= NGRP) return;
    int base = grp * CHUNK;
    int end  = base + CHUNK;
    int lo = 0, hi = N_NODES - 1;                      // largest d: off[d] <= base
    while (lo < hi) {
        int mid = (lo + hi + 1) >> 1;
        if (off[mid] <= base) lo = mid; else hi = mid - 1;
    }
    int d = lo;
    bool dstart_in = (off[d] >= base);
    int next = off[d + 1];
    float2 acc = make_float2(0.f, 0.f);
    for (int j = base; j < end; j += 4) {
        int s0 = ssrc[j], s1 = ssrc[j + 1], s2 = ssrc[j + 2], s3 = ssrc[j + 3];
        __half2 v0 = feat[s0 * L + lane];
        __half2 v1 = feat[s1 * L + lane];
        __half2 v2 = feat[s2 * L + lane];
        __half2 v3 = feat[s3 * L + lane];
        #pragma unroll
        for (int q = 0; q < 4; ++q) {
            int jj = j + q;
            if (jj >= next) {
                if (dstart_in) {
                    agg[d * L + lane] = acc;
                } else {
                    unsafeAtomicAdd(&((float*)agg)[(d * L + lane) * 2],     acc.x);
                    unsafeAtomicAdd(&((float*)agg)[(d * L + lane) * 2 + 1], acc.y);
                }
                acc = make_float2(0.f, 0.f);
                dstart_in = true;
                d++;
                while (off[d + 1] <= jj) d++;
                next = off[d + 1];
            }
            __half2 v = (q == 0) ? v0 : (q == 1) ? v1 : (q == 2) ? v2 : v3;
            float2 f = __half22float2(v);
            acc.x += f.x; acc.y += f.y;
        }
    }
    if (dstart_in && next == end) {
        agg[d * L + lane] = acc;
    } else {
        unsafeAtomicAdd(&((float*)agg)[(d * L + lane) * 2],     acc.x);
        unsafeAtomicAdd(&((float*)agg)[(d * L + lane) * 2 + 1], acc.y);
    }
}

// ---------- dense update 1 ----------
__global__ __launch_bounds__(512)
void k_update1(const float* __restrict__ agg1, const int* __restrict__ deg,
               const __half2* __restrict__ x0h,
               const float* __restrict__ W_l, const float* __restrict__ W_r,
               const float* __restrict__ b, __half* __restrict__ h1h) {
    __shared__ float sWl[HID * 34];
    __shared__ float sWr[HID * 34];
    __shared__ float srow[8][4][64];
    for (int i = threadIdx.x; i < HID * EMBED; i += 512) {
        int o = i >> 5, k = i & 31;
        sWl[o * 34 + k] = W_l[i];
        sWr[o * 34 + k] = W_r[i];
    }
    int w = threadIdx.x >> 6, lane = threadIdx.x & 63;
    int nb = blockIdx.x * 32 + w * 4;
    #pragma unroll
    for (int i = 0; i < 4; ++i) {
        int n = nb + i;
        if (lane < 32) {
            float inv = 1.0f / fmaxf((float)deg[n], 1.0f);
            srow[w][i][lane] = agg1[n * 32 + lane] * inv;
        } else {
            int ch = lane - 32;
            float2 f = __half22float2(x0h[n * 16 + (ch >> 1)]);
            srow[w][i][lane] = ((ch & 1) == 0) ? f.x : f.y;
        }
    }
    __syncthreads();
    float bo = b[lane];
    float a0 = 0, a1 = 0, a2 = 0, a3 = 0;
    #pragma unroll
    for (int k = 0; k < 32; ++k) {
        float wl = sWl[lane * 34 + k];
        float wr = sWr[lane * 34 + k];
        a0 += srow[w][0][k] * wl + srow[w][0][32 + k] * wr;
        a1 += srow[w][1][k] * wl + srow[w][1][32 + k] * wr;
        a2 += srow[w][2][k] * wl + srow[w][2][32 + k] * wr;
        a3 += srow[w][3][k] * wl + srow[w][3][32 + k] * wr;
    }
    h1h[(nb + 0) * HID + lane] = __float2half(fmaxf(a0 + bo, 0.f));
    h1h[(nb + 1) * HID + lane] = __float2half(fmaxf(a1 + bo, 0.f));
    h1h[(nb + 2) * HID + lane] = __float2half(fmaxf(a2 + bo, 0.f));
    h1h[(nb + 3) * HID + lane] = __float2half(fmaxf(a3 + bo, 0.f));
}

// ---------- dense update 2 ----------
__global__ __launch_bounds__(512)
void k_update2(const float* __restrict__ agg2, const int* __restrict__ deg,
               const __half* __restrict__ h1h,
               const float* __restrict__ W_l, const float* __restrict__ W_r,
               const float* __restrict__ b, __half* __restrict__ h2h) {
    __shared__ float sWl[HID * 66];
    __shared__ float sWr[HID * 66];
    __shared__ float srow[8][4][128];
    for (int i = threadIdx.x; i < HID * HID; i += 512) {
        int o = i >> 6, k = i & 63;
        sWl[o * 66 + k] = W_l[i];
        sWr[o * 66 + k] = W_r[i];
    }
    int w = threadIdx.x >> 6, lane = threadIdx.x & 63;
    int nb = blockIdx.x * 32 + w * 4;
    #pragma unroll
    for (int i = 0; i < 4; ++i) {
        int n = nb + i;
        float inv = 1.0f / fmaxf((float)deg[n], 1.0f);
        srow[w][i][lane]      = agg2[n * 64 + lane] * inv;
        srow[w][i][64 + lane] = __half2float(h1h[n * 64 + lane]);
    }
    __syncthreads();
    float bo = b[lane];
    float a0 = 0, a1 = 0, a2 = 0, a3 = 0;
    #pragma unroll
    for (int k = 0; k < 64; ++k) {
        float wl = sWl[lane * 66 + k];
        float wr = sWr[lane * 66 + k];
        a0 += srow[w][0][k] * wl + srow[w][0][64 + k] * wr;
        a1 += srow[w][1][k] * wl + srow[w][1][64 + k] * wr;
        a2 += srow[w][2][k] * wl + srow[w][2][64 + k] * wr;
        a3 += srow[w][3][k] * wl + srow[w][3][64 + k] * wr;
    }
    h2h[(nb + 0) * HID + lane] = __float2half(fmaxf(a0 + bo, 0.f));
    h2h[(nb + 1) * HID + lane] = __float2half(fmaxf(a1 + bo, 0.f));
    h2h[(nb + 2) * HID + lane] = __float2half(fmaxf(a2 + bo, 0.f));
    h2h[(nb + 3) * HID + lane] = __float2half(fmaxf(a3 + bo, 0.f));
}

// ---------- pool + final head ----------
__device__ inline int lower_bound_batch(const int* b, int val) {
    int lo = 0, hi = N_NODES;
    while (lo < hi) {
        int mid = (lo + hi) >> 1;
        if (b[mid] < val) lo = mid + 1; else hi = mid;
    }
    return lo;
}

__global__ __launch_bounds__(256)
void k_pool_final(const __half* __restrict__ h2h, const int* __restrict__ batch,
                  const float* __restrict__ W_lin, const float* __restrict__ b_lin,
                  float* __restrict__ out) {
    __shared__ float red[4][64];
    __shared__ float pool[64];
    int g = blockIdx.x;
    int start = lower_bound_batch(batch, g);
    int end   = lower_bound_batch(batch, g + 1);
    int w = threadIdx.x >> 6, lane = threadIdx.x & 63;
    float acc = 0.0f;
    for (int n = start + w; n < end; n += 4)
        acc += __half2float(h2h[(size_t)n * HID + lane]);
    red[w][lane] = acc;
    __syncthreads();
    if (w == 0) {
        float tot = red[0][lane] + red[1][lane] + red[2][lane] + red[3][lane];
        pool[lane] = tot / fmaxf((float)(end - start), 1.0f);
    }
    __syncthreads();
    if (threadIdx.x < 2) {
        int c = threadIdx.x;
        float s = b_lin[c];
        #pragma unroll 8
        for (int k = 0; k < HID; ++k)
            s += pool[k] * W_lin[c * HID + k];
        out[g * 2 + c] = s;
    }
}

extern "C" void kernel_launch(void* const* d_in, const int* in_sizes, int n_in,
                              void* d_out, int out_size, void* d_ws, size_t ws_size,
                              hipStream_t stream) {
    const int*   node_ids = (const int*)d_in[0];
    const int*   ei       = (const int*)d_in[1];
    const int*   batch    = (const int*)d_in[2];
    const float* table    = (const float*)d_in[3];
    const float* W1l      = (const float*)d_in[4];
    const float* W1r      = (const float*)d_in[5];
    const float* b1       = (const float*)d_in[6];
    const float* W2l      = (const float*)d_in[7];
    const float* W2r      = (const float*)d_in[8];
    const float* b2       = (const float*)d_in[9];
    const float* Wlin     = (const float*)d_in[10];
    const float* blin     = (const float*)d_in[11];
    const int* src = ei;
    const int* dst = ei + N_EDGES;

    int* bcnt  = (int*)d_ws;                                 // 1568*16 (line-padded)
    int* bbase = bcnt + 1568 * 16;                           // 1568
    int* ideg  = bbase + 1568;                               // N
    int* ioff  = ideg + N_NODES;                             // N+1
    int* ebuf  = ioff + N_NODES + 1;                         // NBUCK*CAP
    int* issrc = ebuf + (size_t)NBUCK * CAP;                 // E
    size_t int_total = 1568 * 16 + 1568 + N_NODES + (N_NODES + 1)
                     + (size_t)NBUCK * CAP + N_EDGES;
    float*   aggAB = (float*)d_ws + int_total + 3;           // 16B aligned, 64N floats
    __half2* x0h   = (__half2*)(aggAB + 64 * N_NODES);       // 16N half2
    __half*  h1h   = (__half*)(x0h + 16 * N_NODES);          // 64N half
    __half*  h2h   = h1h + 64 * N_NODES;                     // 64N half

    hipMemsetAsync(bcnt, 0, 1568 * 16 * sizeof(int), stream);
    hipMemsetAsync(aggAB, 0, 32 * N_NODES * sizeof(float), stream);

    k_embed <<<N_NODES * 16 / 256, 256, 0, stream>>>(node_ids, table, x0h);
    k_part  <<<NPART, 256, 0, stream>>>(src, dst, bcnt, ebuf);
    k_bscan <<<1, 1024, 0, stream>>>(bcnt, bbase, ioff + N_NODES);
    k_sortb <<<NBUCK, 256, 0, stream>>>(bcnt, ebuf, bbase, issrc, ideg, ioff);

    k_agg<16><<<(NGRP * 16 + 255) / 256, 256, 0, stream>>>(issrc, ioff, x0h,
                                                           (float2*)aggAB);
    k_update1<<<N_NODES / 32, 512, 0, stream>>>(aggAB, ideg, x0h, W1l, W1r, b1, h1h);

    hipMemsetAsync(aggAB, 0, 64 * N_NODES * sizeof(float), stream);
    k_agg<32><<<(NGRP * 32 + 255) / 256, 256, 0, stream>>>(issrc, ioff,
                                                           (const __half2*)h1h,
                                                           (float2*)aggAB);
    k_update2<<<N_NODES / 32, 512, 0, stream>>>(aggAB, ideg, h1h, W2l, W2r, b2, h2h);

    k_pool_final<<<N_GRAPHS, 256, 0, stream>>>(h2h, batch, Wlin, blin, (float*)d_out);
}

// Round 7
// 326.774 us; speedup vs baseline: 3.8624x; 1.0219x over previous
//
#include <hip/hip_runtime.h>
#include <hip/hip_fp16.h>

#define N_NODES 100000
#define N_EDGES 1600000
#define N_GRAPHS 128
#define EMBED 32
#define HID 64
#define NBUCK 1563             // ceil(N_NODES/64)
#define CAP 1280               // per-bucket LDS safety cap (mean 1024, sigma 32)
#define CHUNK 128              // edges per agg group
#define NGRP (N_EDGES / CHUNK) // 12500
#define PTILE 8192             // edges per partition tile
#define NTILE ((N_EDGES + PTILE - 1) / PTILE)  // 196
#define TP 200                 // padded tile stride in htile

// ---------- embed gather -> fp16 ----------
__global__ void k_embed(const int* __restrict__ ids,
                        const float* __restrict__ table,
                        __half2* __restrict__ x0h) {
    int gid = blockIdx.x * blockDim.x + threadIdx.x;   // N*16 threads exactly
    int n = gid >> 4, q = gid & 15;
    int id = ids[n];
    float2 t = ((const float2*)(table + (size_t)id * EMBED))[q];
    x0h[(size_t)n * 16 + q] = __floats2half2_rn(t.x, t.y);
}

// ---------- pass A: per-tile bucket histogram + dense bucket totals ----------
__global__ __launch_bounds__(256)
void k_histA(const int* __restrict__ dst, int* __restrict__ bcnt,
             int* __restrict__ htile) {
    __shared__ int hist[NBUCK];
    int tid = threadIdx.x, t = blockIdx.x;
    int e0 = t * PTILE;
    int cnt = min(PTILE, N_EDGES - e0);
    for (int i = tid; i < NBUCK; i += 256) hist[i] = 0;
    __syncthreads();
    for (int i = tid; i < cnt; i += 256)
        atomicAdd(&hist[dst[e0 + i] >> 6], 1);         // native int LDS atomic
    __syncthreads();
    for (int b = tid; b < NBUCK; b += 256) {
        int v = hist[b];
        htile[b * TP + t] = v;
        if (v) atomicAdd(&bcnt[b], v);
    }
}

// ---------- bucket-base scan (dense bcnt -> bbase, total) ----------
__global__ __launch_bounds__(1024)
void k_bscan(const int* __restrict__ bcnt, int* __restrict__ bbase,
             int* __restrict__ off_total) {
    __shared__ int leaf[1024];
    int t = threadIdx.x;
    int i0 = 2 * t, i1 = 2 * t + 1;
    int a = (i0 < NBUCK) ? bcnt[i0] : 0;
    int b = (i1 < NBUCK) ? bcnt[i1] : 0;
    leaf[t] = a + b;
    __syncthreads();
    for (int d = 1; d < 1024; d <<= 1) {
        int v = (t >= d) ? leaf[t - d] : 0;
        __syncthreads();
        leaf[t] += v;
        __syncthreads();
    }
    int excl = leaf[t] - (a + b);
    if (i0 < NBUCK) bbase[i0] = excl;
    if (i1 < NBUCK) bbase[i1] = excl + a;
    if (t == 1023) off_total[0] = leaf[1023];          // = E
}

// ---------- pass B: per-bucket prefix over tiles -> dense write bases ----------
__global__ __launch_bounds__(256)
void k_scanB(int* __restrict__ htile, const int* __restrict__ bbase) {
    int b = blockIdx.x * 256 + threadIdx.x;
    if (b >= NBUCK) return;
    int run = bbase[b];
    int* row = htile + b * TP;
    for (int t = 0; t < NTILE; ++t) {
        int v = row[t];
        row[t] = run;
        run += v;
    }
}

// ---------- pass C: scatter edges to dense bucket-grouped epk ----------
__global__ __launch_bounds__(256)
void k_scatC(const int* __restrict__ src, const int* __restrict__ dst,
             const int* __restrict__ htile, int* __restrict__ epk) {
    __shared__ int cur[NBUCK];
    // bijective XCD swizzle: adjacent tiles -> same XCD (adjacent runs share lines)
    int orig = blockIdx.x;
    int xcd = orig & 7, idx = orig >> 3;
    const int q = NTILE >> 3, r = NTILE & 7;           // 24, 4
    int t = (xcd < r ? xcd * (q + 1) : r * (q + 1) + (xcd - r) * q) + idx;
    int tid = threadIdx.x;
    int e0 = t * PTILE;
    int cnt = min(PTILE, N_EDGES - e0);
    for (int b = tid; b < NBUCK; b += 256) cur[b] = htile[b * TP + t];
    __syncthreads();
    for (int i = tid; i < cnt; i += 256) {
        int d = dst[e0 + i];
        int s = src[e0 + i];
        int b = d >> 6;
        int pos = atomicAdd(&cur[b], 1);               // LDS int atomic
        epk[pos] = s | ((d & 63) << 17);
    }
}

// ---------- level-2: per-bucket counting sort (wave-replicated hist) ----------
__global__ __launch_bounds__(256)
void k_sortb(const int* __restrict__ bcnt, const int* __restrict__ epk,
             const int* __restrict__ bbase,
             int* __restrict__ ssrc, int* __restrict__ deg, int* __restrict__ off) {
    __shared__ int hist4[4][64];
    __shared__ int loff[64];
    __shared__ int cur4[4][64];
    int tid = threadIdx.x, bkt = blockIdx.x;
    int w = tid >> 6, lane = tid & 63;
    int base = bbase[bkt];
    int cntE = min(bcnt[bkt], CAP);
    hist4[w][lane] = 0;
    __syncthreads();
    const int* eb = epk + base;
    int v[5]; bool have[5];
    #pragma unroll
    for (int qq = 0; qq < 5; ++qq) {                   // 5*256 = 1280 = CAP
        int i = qq * 256 + tid;
        have[qq] = (i < cntE);
        if (have[qq]) {
            v[qq] = eb[i];
            atomicAdd(&hist4[w][v[qq] >> 17], 1);
        }
    }
    __syncthreads();
    if (tid < 64) {
        int h0 = hist4[0][tid], h1 = hist4[1][tid];
        int h2 = hist4[2][tid], h3 = hist4[3][tid];
        int h = h0 + h1 + h2 + h3;
        int inc = h;
        for (int d = 1; d < 64; d <<= 1) {
            int u = __shfl_up(inc, d);
            if (tid >= d) inc += u;
        }
        int excl = inc - h;
        loff[tid] = excl;
        cur4[0][tid] = excl;
        cur4[1][tid] = excl + h0;
        cur4[2][tid] = excl + h0 + h1;
        cur4[3][tid] = excl + h0 + h1 + h2;
        int n0 = bkt << 6;
        if (n0 + tid < N_NODES) {
            deg[n0 + tid] = h;
            off[n0 + tid] = base + excl;
        }
    }
    __syncthreads();
    #pragma unroll
    for (int qq = 0; qq < 5; ++qq) {
        if (have[qq]) {
            int l = v[qq] >> 17;
            int pos = atomicAdd(&cur4[w][l], 1);
            ssrc[base + pos] = v[qq] & 0x1FFFF;        // 4KB region, one block/XCD
        }
    }
}

// ---------- edge-streaming segmented aggregation ----------
template<int L>
__global__ __launch_bounds__(256)
void k_agg(const int* __restrict__ ssrc, const int* __restrict__ off,
           const __half2* __restrict__ feat,   // [N][L] half2
           float2* __restrict__ agg)           // [N][L] float2
{
    int tid = blockIdx.x * 256 + threadIdx.x;
    int grp = tid / L;
    int lane = tid % L;
    if (grp >= NGRP) return;
    int base = grp * CHUNK;
    int end  = base + CHUNK;
    int lo = 0, hi = N_NODES - 1;                      // largest d: off[d] <= base
    while (lo < hi) {
        int mid = (lo + hi + 1) >> 1;
        if (off[mid] <= base) lo = mid; else hi = mid - 1;
    }
    int d = lo;
    bool dstart_in = (off[d] >= base);
    int next = off[d + 1];
    float2 acc = make_float2(0.f, 0.f);
    for (int j = base; j < end; j += 4) {
        int s0 = ssrc[j], s1 = ssrc[j + 1], s2 = ssrc[j + 2], s3 = ssrc[j + 3];
        __half2 v0 = feat[s0 * L + lane];
        __half2 v1 = feat[s1 * L + lane];
        __half2 v2 = feat[s2 * L + lane];
        __half2 v3 = feat[s3 * L + lane];
        #pragma unroll
        for (int q = 0; q < 4; ++q) {
            int jj = j + q;
            if (jj >= next) {
                if (dstart_in) {
                    agg[d * L + lane] = acc;
                } else {
                    unsafeAtomicAdd(&((float*)agg)[(d * L + lane) * 2],     acc.x);
                    unsafeAtomicAdd(&((float*)agg)[(d * L + lane) * 2 + 1], acc.y);
                }
                acc = make_float2(0.f, 0.f);
                dstart_in = true;
                d++;
                while (off[d + 1] <= jj) d++;
                next = off[d + 1];
            }
            __half2 v = (q == 0) ? v0 : (q == 1) ? v1 : (q == 2) ? v2 : v3;
            float2 f = __half22float2(v);
            acc.x += f.x; acc.y += f.y;
        }
    }
    if (dstart_in && next == end) {
        agg[d * L + lane] = acc;
    } else {
        unsafeAtomicAdd(&((float*)agg)[(d * L + lane) * 2],     acc.x);
        unsafeAtomicAdd(&((float*)agg)[(d * L + lane) * 2 + 1], acc.y);
    }
}

// ---------- dense update 1 ----------
__global__ __launch_bounds__(512)
void k_update1(const float* __restrict__ agg1, const int* __restrict__ deg,
               const __half2* __restrict__ x0h,
               const float* __restrict__ W_l, const float* __restrict__ W_r,
               const float* __restrict__ b, __half* __restrict__ h1h) {
    __shared__ float sWl[HID * 34];
    __shared__ float sWr[HID * 34];
    __shared__ float srow[8][4][64];
    for (int i = threadIdx.x; i < HID * EMBED; i += 512) {
        int o = i >> 5, k = i & 31;
        sWl[o * 34 + k] = W_l[i];
        sWr[o * 34 + k] = W_r[i];
    }
    int w = threadIdx.x >> 6, lane = threadIdx.x & 63;
    int nb = blockIdx.x * 32 + w * 4;
    #pragma unroll
    for (int i = 0; i < 4; ++i) {
        int n = nb + i;
        if (lane < 32) {
            float inv = 1.0f / fmaxf((float)deg[n], 1.0f);
            srow[w][i][lane] = agg1[n * 32 + lane] * inv;
        } else {
            int ch = lane - 32;
            float2 f = __half22float2(x0h[n * 16 + (ch >> 1)]);
            srow[w][i][lane] = ((ch & 1) == 0) ? f.x : f.y;
        }
    }
    __syncthreads();
    float bo = b[lane];
    float a0 = 0, a1 = 0, a2 = 0, a3 = 0;
    #pragma unroll
    for (int k = 0; k < 32; ++k) {
        float wl = sWl[lane * 34 + k];
        float wr = sWr[lane * 34 + k];
        a0 += srow[w][0][k] * wl + srow[w][0][32 + k] * wr;
        a1 += srow[w][1][k] * wl + srow[w][1][32 + k] * wr;
        a2 += srow[w][2][k] * wl + srow[w][2][32 + k] * wr;
        a3 += srow[w][3][k] * wl + srow[w][3][32 + k] * wr;
    }
    h1h[(nb + 0) * HID + lane] = __float2half(fmaxf(a0 + bo, 0.f));
    h1h[(nb + 1) * HID + lane] = __float2half(fmaxf(a1 + bo, 0.f));
    h1h[(nb + 2) * HID + lane] = __float2half(fmaxf(a2 + bo, 0.f));
    h1h[(nb + 3) * HID + lane] = __float2half(fmaxf(a3 + bo, 0.f));
}

// ---------- dense update 2 ----------
__global__ __launch_bounds__(512)
void k_update2(const float* __restrict__ agg2, const int* __restrict__ deg,
               const __half* __restrict__ h1h,
               const float* __restrict__ W_l, const float* __restrict__ W_r,
               const float* __restrict__ b, __half* __restrict__ h2h) {
    __shared__ float sWl[HID * 66];
    __shared__ float sWr[HID * 66];
    __shared__ float srow[8][4][128];
    for (int i = threadIdx.x; i < HID * HID; i += 512) {
        int o = i >> 6, k = i & 63;
        sWl[o * 66 + k] = W_l[i];
        sWr[o * 66 + k] = W_r[i];
    }
    int w = threadIdx.x >> 6, lane = threadIdx.x & 63;
    int nb = blockIdx.x * 32 + w * 4;
    #pragma unroll
    for (int i = 0; i < 4; ++i) {
        int n = nb + i;
        float inv = 1.0f / fmaxf((float)deg[n], 1.0f);
        srow[w][i][lane]      = agg2[n * 64 + lane] * inv;
        srow[w][i][64 + lane] = __half2float(h1h[n * 64 + lane]);
    }
    __syncthreads();
    float bo = b[lane];
    float a0 = 0, a1 = 0, a2 = 0, a3 = 0;
    #pragma unroll
    for (int k = 0; k < 64; ++k) {
        float wl = sWl[lane * 66 + k];
        float wr = sWr[lane * 66 + k];
        a0 += srow[w][0][k] * wl + srow[w][0][64 + k] * wr;
        a1 += srow[w][1][k] * wl + srow[w][1][64 + k] * wr;
        a2 += srow[w][2][k] * wl + srow[w][2][64 + k] * wr;
        a3 += srow[w][3][k] * wl + srow[w][3][64 + k] * wr;
    }
    h2h[(nb + 0) * HID + lane] = __float2half(fmaxf(a0 + bo, 0.f));
    h2h[(nb + 1) * HID + lane] = __float2half(fmaxf(a1 + bo, 0.f));
    h2h[(nb + 2) * HID + lane] = __float2half(fmaxf(a2 + bo, 0.f));
    h2h[(nb + 3) * HID + lane] = __float2half(fmaxf(a3 + bo, 0.f));
}

// ---------- pool + final head ----------
__device__ inline int lower_bound_batch(const int* b, int val) {
    int lo = 0, hi = N_NODES;
    while (lo < hi) {
        int mid = (lo + hi) >> 1;
        if (b[mid] < val) lo = mid + 1; else hi = mid;
    }
    return lo;
}

__global__ __launch_bounds__(256)
void k_pool_final(const __half* __restrict__ h2h, const int* __restrict__ batch,
                  const float* __restrict__ W_lin, const float* __restrict__ b_lin,
                  float* __restrict__ out) {
    __shared__ float red[4][64];
    __shared__ float pool[64];
    int g = blockIdx.x;
    int start = lower_bound_batch(batch, g);
    int end   = lower_bound_batch(batch, g + 1);
    int w = threadIdx.x >> 6, lane = threadIdx.x & 63;
    float acc = 0.0f;
    for (int n = start + w; n < end; n += 4)
        acc += __half2float(h2h[(size_t)n * HID + lane]);
    red[w][lane] = acc;
    __syncthreads();
    if (w == 0) {
        float tot = red[0][lane] + red[1][lane] + red[2][lane] + red[3][lane];
        pool[lane] = tot / fmaxf((float)(end - start), 1.0f);
    }
    __syncthreads();
    if (threadIdx.x < 2) {
        int c = threadIdx.x;
        float s = b_lin[c];
        #pragma unroll 8
        for (int k = 0; k < HID; ++k)
            s += pool[k] * W_lin[c * HID + k];
        out[g * 2 + c] = s;
    }
}

extern "C" void kernel_launch(void* const* d_in, const int* in_sizes, int n_in,
                              void* d_out, int out_size, void* d_ws, size_t ws_size,
                              hipStream_t stream) {
    const int*   node_ids = (const int*)d_in[0];
    const int*   ei       = (const int*)d_in[1];
    const int*   batch    = (const int*)d_in[2];
    const float* table    = (const float*)d_in[3];
    const float* W1l      = (const float*)d_in[4];
    const float* W1r      = (const float*)d_in[5];
    const float* b1       = (const float*)d_in[6];
    const float* W2l      = (const float*)d_in[7];
    const float* W2r      = (const float*)d_in[8];
    const float* b2       = (const float*)d_in[9];
    const float* Wlin     = (const float*)d_in[10];
    const float* blin     = (const float*)d_in[11];
    const int* src = ei;
    const int* dst = ei + N_EDGES;

    // ints: bcnt[1600] bbase[1600] deg[N] off[N+1] htile[NBUCK*TP] epk[E] ssrc[E]
    int* bcnt  = (int*)d_ws;                                 // 1600 (zeroed)
    int* bbase = bcnt + 1600;                                // 1600
    int* ideg  = bbase + 1600;                               // N
    int* ioff  = ideg + N_NODES;                             // N+1
    int* htile = ioff + N_NODES + 1;                         // NBUCK*TP = 312600
    int* epk   = htile + (size_t)NBUCK * TP;                 // E
    int* issrc = epk + N_EDGES;                              // E
    size_t int_total = 1600 + 1600 + N_NODES + (N_NODES + 1)
                     + (size_t)NBUCK * TP + N_EDGES + N_EDGES;   // 3,715,801
    float*   aggAB = (float*)d_ws + int_total + 3;           // 16B-aligned, 64N floats
    __half2* x0h   = (__half2*)(aggAB + 64 * N_NODES);       // 16N half2
    __half*  h1h   = (__half*)(x0h + 16 * N_NODES);          // 64N half
    __half*  h2h   = h1h + 64 * N_NODES;                     // 64N half

    hipMemsetAsync(bcnt, 0, 1600 * sizeof(int), stream);
    hipMemsetAsync(aggAB, 0, 32 * N_NODES * sizeof(float), stream);

    k_embed<<<N_NODES * 16 / 256, 256, 0, stream>>>(node_ids, table, x0h);
    k_histA<<<NTILE, 256, 0, stream>>>(dst, bcnt, htile);
    k_bscan<<<1, 1024, 0, stream>>>(bcnt, bbase, ioff + N_NODES);
    k_scanB<<<(NBUCK + 255) / 256, 256, 0, stream>>>(htile, bbase);
    k_scatC<<<NTILE, 256, 0, stream>>>(src, dst, htile, epk);
    k_sortb<<<NBUCK, 256, 0, stream>>>(bcnt, epk, bbase, issrc, ideg, ioff);

    k_agg<16><<<(NGRP * 16 + 255) / 256, 256, 0, stream>>>(issrc, ioff, x0h,
                                                           (float2*)aggAB);
    k_update1<<<N_NODES / 32, 512, 0, stream>>>(aggAB, ideg, x0h, W1l, W1r, b1, h1h);

    hipMemsetAsync(aggAB, 0, 64 * N_NODES * sizeof(float), stream);
    k_agg<32><<<(NGRP * 32 + 255) / 256, 256, 0, stream>>>(issrc, ioff,
                                                           (const __half2*)h1h,
                                                           (float2*)aggAB);
    k_update2<<<N_NODES / 32, 512, 0, stream>>>(aggAB, ideg, h1h, W2l, W2r, b2, h2h);

    k_pool_final<<<N_GRAPHS, 256, 0, stream>>>(h2h, batch, Wlin, blin, (float*)d_out);
}

// Round 8
// 296.552 us; speedup vs baseline: 4.2560x; 1.1019x over previous
//
#include <hip/hip_runtime.h>
#include <hip/hip_fp16.h>

#define N_NODES 100000
#define N_EDGES 1600000
#define N_GRAPHS 128
#define EMBED 32
#define HID 64
#define NBUCK 1563             // ceil(N_NODES/64)
#define CAP 1280               // per-bucket LDS safety cap (mean 1024, sigma 32)
#define CHUNK 128              // edges per agg group
#define NGRP (N_EDGES / CHUNK) // 12500
#define PTILE 8192             // edges per partition tile
#define NTILE ((N_EDGES + PTILE - 1) / PTILE)  // 196
#define TP 200                 // padded tile stride in htile
#define NPGRP 2048             // pooling groups
#define PPER ((N_NODES + NPGRP - 1) / NPGRP)   // 49 nodes per group

// ---------- embed gather -> fp16 ----------
__global__ void k_embed(const int* __restrict__ ids,
                        const float* __restrict__ table,
                        __half2* __restrict__ x0h) {
    int gid = blockIdx.x * blockDim.x + threadIdx.x;   // N*16 threads exactly
    int n = gid >> 4, q = gid & 15;
    int id = ids[n];
    float2 t = ((const float2*)(table + (size_t)id * EMBED))[q];
    x0h[(size_t)n * 16 + q] = __floats2half2_rn(t.x, t.y);
}

// ---------- pass A: per-tile bucket histogram + dense bucket totals ----------
__global__ __launch_bounds__(256)
void k_histA(const int* __restrict__ dst, int* __restrict__ bcnt,
             int* __restrict__ htile) {
    __shared__ int hist[NBUCK];
    int tid = threadIdx.x, t = blockIdx.x;
    int e0 = t * PTILE;
    int cnt = min(PTILE, N_EDGES - e0);
    for (int i = tid; i < NBUCK; i += 256) hist[i] = 0;
    __syncthreads();
    for (int i = tid; i < cnt; i += 256)
        atomicAdd(&hist[dst[e0 + i] >> 6], 1);         // native int LDS atomic
    __syncthreads();
    for (int b = tid; b < NBUCK; b += 256) {
        int v = hist[b];
        htile[b * TP + t] = v;
        if (v) atomicAdd(&bcnt[b], v);
    }
}

// ---------- bucket-base scan (dense bcnt -> bbase, total) ----------
__global__ __launch_bounds__(1024)
void k_bscan(const int* __restrict__ bcnt, int* __restrict__ bbase,
             int* __restrict__ off_total) {
    __shared__ int leaf[1024];
    int t = threadIdx.x;
    int i0 = 2 * t, i1 = 2 * t + 1;
    int a = (i0 < NBUCK) ? bcnt[i0] : 0;
    int b = (i1 < NBUCK) ? bcnt[i1] : 0;
    leaf[t] = a + b;
    __syncthreads();
    for (int d = 1; d < 1024; d <<= 1) {
        int v = (t >= d) ? leaf[t - d] : 0;
        __syncthreads();
        leaf[t] += v;
        __syncthreads();
    }
    int excl = leaf[t] - (a + b);
    if (i0 < NBUCK) bbase[i0] = excl;
    if (i1 < NBUCK) bbase[i1] = excl + a;
    if (t == 1023) off_total[0] = leaf[1023];          // = E
}

// ---------- pass B: per-bucket prefix over tiles -> dense write bases ----------
__global__ __launch_bounds__(256)
void k_scanB(int* __restrict__ htile, const int* __restrict__ bbase) {
    int b = blockIdx.x * 256 + threadIdx.x;
    if (b >= NBUCK) return;
    int run = bbase[b];
    int* row = htile + b * TP;
    for (int t = 0; t < NTILE; ++t) {
        int v = row[t];
        row[t] = run;
        run += v;
    }
}

// ---------- pass C: scatter edges to dense bucket-grouped epk ----------
__global__ __launch_bounds__(256)
void k_scatC(const int* __restrict__ src, const int* __restrict__ dst,
             const int* __restrict__ htile, int* __restrict__ epk) {
    __shared__ int cur[NBUCK];
    // bijective XCD swizzle: adjacent tiles -> same XCD (adjacent runs share lines)
    int orig = blockIdx.x;
    int xcd = orig & 7, idx = orig >> 3;
    const int q = NTILE >> 3, r = NTILE & 7;           // 24, 4
    int t = (xcd < r ? xcd * (q + 1) : r * (q + 1) + (xcd - r) * q) + idx;
    int tid = threadIdx.x;
    int e0 = t * PTILE;
    int cnt = min(PTILE, N_EDGES - e0);
    for (int b = tid; b < NBUCK; b += 256) cur[b] = htile[b * TP + t];
    __syncthreads();
    for (int i = tid; i < cnt; i += 256) {
        int d = dst[e0 + i];
        int s = src[e0 + i];
        int b = d >> 6;
        int pos = atomicAdd(&cur[b], 1);               // LDS int atomic
        epk[pos] = s | ((d & 63) << 17);
    }
}

// ---------- level-2: per-bucket counting sort (wave-replicated hist) ----------
__global__ __launch_bounds__(256)
void k_sortb(const int* __restrict__ bcnt, const int* __restrict__ epk,
             const int* __restrict__ bbase,
             int* __restrict__ ssrc, int* __restrict__ deg, int* __restrict__ off) {
    __shared__ int hist4[4][64];
    __shared__ int loff[64];
    __shared__ int cur4[4][64];
    int tid = threadIdx.x, bkt = blockIdx.x;
    int w = tid >> 6, lane = tid & 63;
    int base = bbase[bkt];
    int cntE = min(bcnt[bkt], CAP);
    hist4[w][lane] = 0;
    __syncthreads();
    const int* eb = epk + base;
    int v[5]; bool have[5];
    #pragma unroll
    for (int qq = 0; qq < 5; ++qq) {                   // 5*256 = 1280 = CAP
        int i = qq * 256 + tid;
        have[qq] = (i < cntE);
        if (have[qq]) {
            v[qq] = eb[i];
            atomicAdd(&hist4[w][v[qq] >> 17], 1);
        }
    }
    __syncthreads();
    if (tid < 64) {
        int h0 = hist4[0][tid], h1 = hist4[1][tid];
        int h2 = hist4[2][tid], h3 = hist4[3][tid];
        int h = h0 + h1 + h2 + h3;
        int inc = h;
        for (int d = 1; d < 64; d <<= 1) {
            int u = __shfl_up(inc, d);
            if (tid >= d) inc += u;
        }
        int excl = inc - h;
        loff[tid] = excl;
        cur4[0][tid] = excl;
        cur4[1][tid] = excl + h0;
        cur4[2][tid] = excl + h0 + h1;
        cur4[3][tid] = excl + h0 + h1 + h2;
        int n0 = bkt << 6;
        if (n0 + tid < N_NODES) {
            deg[n0 + tid] = h;
            off[n0 + tid] = base + excl;
        }
    }
    __syncthreads();
    #pragma unroll
    for (int qq = 0; qq < 5; ++qq) {
        if (have[qq]) {
            int l = v[qq] >> 17;
            int pos = atomicAdd(&cur4[w][l], 1);
            ssrc[base + pos] = v[qq] & 0x1FFFF;
        }
    }
}

// ---------- edge-streaming segmented aggregation ----------
template<int L>
__global__ __launch_bounds__(256)
void k_agg(const int* __restrict__ ssrc, const int* __restrict__ off,
           const __half2* __restrict__ feat,   // [N][L] half2
           float2* __restrict__ agg)           // [N][L] float2
{
    int tid = blockIdx.x * 256 + threadIdx.x;
    int grp = tid / L;
    int lane = tid % L;
    if (grp >= NGRP) return;
    int base = grp * CHUNK;
    int end  = base + CHUNK;
    int lo = 0, hi = N_NODES - 1;                      // largest d: off[d] <= base
    while (lo < hi) {
        int mid = (lo + hi + 1) >> 1;
        if (off[mid] <= base) lo = mid; else hi = mid - 1;
    }
    int d = lo;
    bool dstart_in = (off[d] >= base);
    int next = off[d + 1];
    float2 acc = make_float2(0.f, 0.f);
    for (int j = base; j < end; j += 4) {
        int s0 = ssrc[j], s1 = ssrc[j + 1], s2 = ssrc[j + 2], s3 = ssrc[j + 3];
        __half2 v0 = feat[s0 * L + lane];
        __half2 v1 = feat[s1 * L + lane];
        __half2 v2 = feat[s2 * L + lane];
        __half2 v3 = feat[s3 * L + lane];
        #pragma unroll
        for (int q = 0; q < 4; ++q) {
            int jj = j + q;
            if (jj >= next) {
                if (dstart_in) {
                    agg[d * L + lane] = acc;
                } else {
                    unsafeAtomicAdd(&((float*)agg)[(d * L + lane) * 2],     acc.x);
                    unsafeAtomicAdd(&((float*)agg)[(d * L + lane) * 2 + 1], acc.y);
                }
                acc = make_float2(0.f, 0.f);
                dstart_in = true;
                d++;
                while (off[d + 1] <= jj) d++;
                next = off[d + 1];
            }
            __half2 v = (q == 0) ? v0 : (q == 1) ? v1 : (q == 2) ? v2 : v3;
            float2 f = __half22float2(v);
            acc.x += f.x; acc.y += f.y;
        }
    }
    if (dstart_in && next == end) {
        agg[d * L + lane] = acc;
    } else {
        unsafeAtomicAdd(&((float*)agg)[(d * L + lane) * 2],     acc.x);
        unsafeAtomicAdd(&((float*)agg)[(d * L + lane) * 2 + 1], acc.y);
    }
}

// ---------- dense update 1 ----------
__global__ __launch_bounds__(512)
void k_update1(const float* __restrict__ agg1, const int* __restrict__ deg,
               const __half2* __restrict__ x0h,
               const float* __restrict__ W_l, const float* __restrict__ W_r,
               const float* __restrict__ b, __half* __restrict__ h1h) {
    __shared__ float sWl[HID * 34];
    __shared__ float sWr[HID * 34];
    __shared__ float srow[8][4][64];
    for (int i = threadIdx.x; i < HID * EMBED; i += 512) {
        int o = i >> 5, k = i & 31;
        sWl[o * 34 + k] = W_l[i];
        sWr[o * 34 + k] = W_r[i];
    }
    int w = threadIdx.x >> 6, lane = threadIdx.x & 63;
    int nb = blockIdx.x * 32 + w * 4;
    #pragma unroll
    for (int i = 0; i < 4; ++i) {
        int n = nb + i;
        if (lane < 32) {
            float inv = 1.0f / fmaxf((float)deg[n], 1.0f);
            srow[w][i][lane] = agg1[n * 32 + lane] * inv;
        } else {
            int ch = lane - 32;
            float2 f = __half22float2(x0h[n * 16 + (ch >> 1)]);
            srow[w][i][lane] = ((ch & 1) == 0) ? f.x : f.y;
        }
    }
    __syncthreads();
    float bo = b[lane];
    float a0 = 0, a1 = 0, a2 = 0, a3 = 0;
    #pragma unroll
    for (int k = 0; k < 32; ++k) {
        float wl = sWl[lane * 34 + k];
        float wr = sWr[lane * 34 + k];
        a0 += srow[w][0][k] * wl + srow[w][0][32 + k] * wr;
        a1 += srow[w][1][k] * wl + srow[w][1][32 + k] * wr;
        a2 += srow[w][2][k] * wl + srow[w][2][32 + k] * wr;
        a3 += srow[w][3][k] * wl + srow[w][3][32 + k] * wr;
    }
    h1h[(nb + 0) * HID + lane] = __float2half(fmaxf(a0 + bo, 0.f));
    h1h[(nb + 1) * HID + lane] = __float2half(fmaxf(a1 + bo, 0.f));
    h1h[(nb + 2) * HID + lane] = __float2half(fmaxf(a2 + bo, 0.f));
    h1h[(nb + 3) * HID + lane] = __float2half(fmaxf(a3 + bo, 0.f));
}

// ---------- dense update 2 ----------
__global__ __launch_bounds__(512)
void k_update2(const float* __restrict__ agg2, const int* __restrict__ deg,
               const __half* __restrict__ h1h,
               const float* __restrict__ W_l, const float* __restrict__ W_r,
               const float* __restrict__ b, __half* __restrict__ h2h) {
    __shared__ float sWl[HID * 66];
    __shared__ float sWr[HID * 66];
    __shared__ float srow[8][4][128];
    for (int i = threadIdx.x; i < HID * HID; i += 512) {
        int o = i >> 6, k = i & 63;
        sWl[o * 66 + k] = W_l[i];
        sWr[o * 66 + k] = W_r[i];
    }
    int w = threadIdx.x >> 6, lane = threadIdx.x & 63;
    int nb = blockIdx.x * 32 + w * 4;
    #pragma unroll
    for (int i = 0; i < 4; ++i) {
        int n = nb + i;
        float inv = 1.0f / fmaxf((float)deg[n], 1.0f);
        srow[w][i][lane]      = agg2[n * 64 + lane] * inv;
        srow[w][i][64 + lane] = __half2float(h1h[n * 64 + lane]);
    }
    __syncthreads();
    float bo = b[lane];
    float a0 = 0, a1 = 0, a2 = 0, a3 = 0;
    #pragma unroll
    for (int k = 0; k < 64; ++k) {
        float wl = sWl[lane * 66 + k];
        float wr = sWr[lane * 66 + k];
        a0 += srow[w][0][k] * wl + srow[w][0][64 + k] * wr;
        a1 += srow[w][1][k] * wl + srow[w][1][64 + k] * wr;
        a2 += srow[w][2][k] * wl + srow[w][2][64 + k] * wr;
        a3 += srow[w][3][k] * wl + srow[w][3][64 + k] * wr;
    }
    h2h[(nb + 0) * HID + lane] = __float2half(fmaxf(a0 + bo, 0.f));
    h2h[(nb + 1) * HID + lane] = __float2half(fmaxf(a1 + bo, 0.f));
    h2h[(nb + 2) * HID + lane] = __float2half(fmaxf(a2 + bo, 0.f));
    h2h[(nb + 3) * HID + lane] = __float2half(fmaxf(a3 + bo, 0.f));
}

// ---------- pool part 1: run-length accumulate over sorted batch (all CUs) ----------
__global__ __launch_bounds__(256)
void k_pool_part(const __half* __restrict__ h2h, const int* __restrict__ batch,
                 float* __restrict__ pooled, float* __restrict__ gcnt) {
    int grp = blockIdx.x * 4 + (threadIdx.x >> 6);
    int lane = threadIdx.x & 63;
    int start = grp * PPER;
    if (start >= N_NODES) return;
    int end = start + PPER; if (end > N_NODES) end = N_NODES;
    float acc = 0.0f, c = 0.0f;
    int cur = batch[start];
    for (int n = start; n < end; ++n) {
        int bb = batch[n];
        if (bb != cur) {
            unsafeAtomicAdd(&pooled[cur * HID + lane], acc);
            if (lane == 0) unsafeAtomicAdd(&gcnt[cur], c);
            acc = 0.0f; c = 0.0f; cur = bb;
        }
        acc += __half2float(h2h[(size_t)n * HID + lane]);
        c += 1.0f;
    }
    unsafeAtomicAdd(&pooled[cur * HID + lane], acc);
    if (lane == 0) unsafeAtomicAdd(&gcnt[cur], c);
}

// ---------- pool part 2: head ----------
__global__ __launch_bounds__(256)
void k_final(const float* __restrict__ pooled, const float* __restrict__ gcnt,
             const float* __restrict__ W_lin, const float* __restrict__ b_lin,
             float* __restrict__ out) {
    int t = threadIdx.x;          // 256 = 128 graphs * 2 classes
    int g = t >> 1, c = t & 1;
    float inv = 1.0f / fmaxf(gcnt[g], 1.0f);
    float sum = b_lin[c];
    #pragma unroll 8
    for (int k = 0; k < HID; ++k)
        sum += pooled[g * HID + k] * inv * W_lin[c * HID + k];
    out[g * 2 + c] = sum;
}

extern "C" void kernel_launch(void* const* d_in, const int* in_sizes, int n_in,
                              void* d_out, int out_size, void* d_ws, size_t ws_size,
                              hipStream_t stream) {
    const int*   node_ids = (const int*)d_in[0];
    const int*   ei       = (const int*)d_in[1];
    const int*   batch    = (const int*)d_in[2];
    const float* table    = (const float*)d_in[3];
    const float* W1l      = (const float*)d_in[4];
    const float* W1r      = (const float*)d_in[5];
    const float* b1       = (const float*)d_in[6];
    const float* W2l      = (const float*)d_in[7];
    const float* W2r      = (const float*)d_in[8];
    const float* b2       = (const float*)d_in[9];
    const float* Wlin     = (const float*)d_in[10];
    const float* blin     = (const float*)d_in[11];
    const int* src = ei;
    const int* dst = ei + N_EDGES;

    // ints: bcnt[1600] bbase[1600] deg[N] off[N+1] htile[NBUCK*TP] epk[E] ssrc[E]
    int* bcnt  = (int*)d_ws;                                 // 1600 (zeroed)
    int* bbase = bcnt + 1600;                                // 1600
    int* ideg  = bbase + 1600;                               // N
    int* ioff  = ideg + N_NODES;                             // N+1
    int* htile = ioff + N_NODES + 1;                         // NBUCK*TP = 312600
    int* epk   = htile + (size_t)NBUCK * TP;                 // E
    int* issrc = epk + N_EDGES;                              // E
    size_t int_total = 1600 + 1600 + N_NODES + (N_NODES + 1)
                     + (size_t)NBUCK * TP + N_EDGES + N_EDGES;
    float*   aggAB = (float*)d_ws + int_total + 3;           // 16B-aligned, 64N floats
    float*   pooled = aggAB + 64 * N_NODES;                  // 64G floats (zeroed)
    float*   gcnt   = pooled + 64 * N_GRAPHS;                // G floats (zeroed)
    __half2* x0h   = (__half2*)(gcnt + N_GRAPHS);            // 16N half2
    __half*  h1h   = (__half*)(x0h + 16 * N_NODES);          // 64N half
    __half*  h2h   = h1h + 64 * N_NODES;                     // 64N half

    hipMemsetAsync(bcnt, 0, 1600 * sizeof(int), stream);
    hipMemsetAsync(aggAB, 0, 32 * N_NODES * sizeof(float), stream);
    hipMemsetAsync(pooled, 0, 65 * N_GRAPHS * sizeof(float), stream);

    k_embed<<<N_NODES * 16 / 256, 256, 0, stream>>>(node_ids, table, x0h);
    k_histA<<<NTILE, 256, 0, stream>>>(dst, bcnt, htile);
    k_bscan<<<1, 1024, 0, stream>>>(bcnt, bbase, ioff + N_NODES);
    k_scanB<<<(NBUCK + 255) / 256, 256, 0, stream>>>(htile, bbase);
    k_scatC<<<NTILE, 256, 0, stream>>>(src, dst, htile, epk);
    k_sortb<<<NBUCK, 256, 0, stream>>>(bcnt, epk, bbase, issrc, ideg, ioff);

    k_agg<16><<<(NGRP * 16 + 255) / 256, 256, 0, stream>>>(issrc, ioff, x0h,
                                                           (float2*)aggAB);
    k_update1<<<N_NODES / 32, 512, 0, stream>>>(aggAB, ideg, x0h, W1l, W1r, b1, h1h);

    hipMemsetAsync(aggAB, 0, 64 * N_NODES * sizeof(float), stream);
    k_agg<32><<<(NGRP * 32 + 255) / 256, 256, 0, stream>>>(issrc, ioff,
                                                           (const __half2*)h1h,
                                                           (float2*)aggAB);
    k_update2<<<N_NODES / 32, 512, 0, stream>>>(aggAB, ideg, h1h, W2l, W2r, b2, h2h);

    k_pool_part<<<NPGRP / 4, 256, 0, stream>>>(h2h, batch, pooled, gcnt);
    k_final<<<1, 256, 0, stream>>>(pooled, gcnt, Wlin, blin, (float*)d_out);
}